// Round 8
// baseline (260.046 us; speedup 1.0000x reference)
//
#include <hip/hip_runtime.h>
#include <hip/hip_bf16.h>

#define EMBED 1024
#define NHEADS 16
#define HDIM 64
#define SEQ 2048
#define BATCH 4
#define ROWS (BATCH * SEQ) /* 8192 */

typedef __attribute__((ext_vector_type(8))) short bf16x8;   // 8 bf16 = 4 VGPRs
typedef __attribute__((ext_vector_type(4))) float f32x4;
typedef __attribute__((ext_vector_type(2))) float f32x2;
typedef __attribute__((ext_vector_type(16))) float f32x16;
typedef __attribute__((ext_vector_type(4))) unsigned int u32x4;
typedef __attribute__((ext_vector_type(2))) unsigned int u32x2;
typedef __attribute__((ext_vector_type(2))) int i32x2;
typedef unsigned int u32;

#define SL2E 0.18033688011112042f  /* 0.125 * log2(e) */

__device__ __forceinline__ short f2bf(float f) {            // RTNA fp32->bf16 (2 ops)
    u32 u = __builtin_bit_cast(u32, f) + 0x8000u;
    return (short)(u >> 16);
}

__device__ __forceinline__ u32 pkbf(float a, float b) {     // {bf16(a)|bf16(b)<<16}, 3 ops
    u32 ua = __builtin_bit_cast(u32, a) + 0x8000u;
    u32 ub = __builtin_bit_cast(u32, b) + 0x8000u;
    return __builtin_amdgcn_perm(ua, ub, 0x03020706u);      // v_perm_b32: {a.hi16, b.hi16}
}

// single-instruction packed cvt (RTNE): a -> low16, b -> high16 (same order as pkbf)
__device__ __forceinline__ u32 cvtpk(float a, float b) {
    u32 r;
    asm("v_cvt_pk_bf16_f32 %0, %1, %2" : "=v"(r) : "v"(a), "v"(b));
    return r;
}

__device__ __forceinline__ float fexp2(float x) {
#if __has_builtin(__builtin_amdgcn_exp2f)
    return __builtin_amdgcn_exp2f(x);                       // bare v_exp_f32
#else
    return exp2f(x);
#endif
}

__device__ __forceinline__ void async16(const void* g, void* l) {
    __builtin_amdgcn_global_load_lds((const __attribute__((address_space(1))) u32*)g,
                                     (__attribute__((address_space(3))) u32*)l, 16, 0, 0);
}

// ---------- fp32 -> bf16 elementwise (X) ----------
__global__ __launch_bounds__(256) void convert_f32_bf16(const float* __restrict__ in,
                                                        short* __restrict__ out) {
    int i = (blockIdx.x * 256 + threadIdx.x) * 4;
    float4 v = *(const float4*)&in[i];
    u32x2 o = { pkbf(v.x, v.y), pkbf(v.z, v.w) };
    *(u32x2*)&out[i] = o;
}

// ---------- W[K][N] fp32 -> WT[N][K] bf16; z==0 (Wq) pre-scaled by SL2E ----------
__global__ __launch_bounds__(256) void transpose_w4(const float* __restrict__ W0,
                                                    const float* __restrict__ W1,
                                                    const float* __restrict__ W2,
                                                    const float* __restrict__ W3,
                                                    short* __restrict__ T0,
                                                    short* __restrict__ T1,
                                                    short* __restrict__ T2,
                                                    short* __restrict__ T3) {
    const int z = blockIdx.z;
    const float* W = (z == 0) ? W0 : (z == 1) ? W1 : (z == 2) ? W2 : W3;
    short* WT = (z == 0) ? T0 : (z == 1) ? T1 : (z == 2) ? T2 : T3;
    const float sc = (z == 0) ? SL2E : 1.0f;
    __shared__ float T[64][65];
    const int k0 = blockIdx.y * 64, n0 = blockIdx.x * 64;
    const int rr = threadIdx.x >> 4, cc = (threadIdx.x & 15) * 4;
    #pragma unroll
    for (int p = 0; p < 4; ++p) {
        int r = p * 16 + rr;
        float4 v = *(const float4*)&W[(size_t)(k0 + r) * EMBED + n0 + cc];
        T[r][cc] = v.x * sc; T[r][cc + 1] = v.y * sc; T[r][cc + 2] = v.z * sc; T[r][cc + 3] = v.w * sc;
    }
    __syncthreads();
    #pragma unroll
    for (int p = 0; p < 4; ++p) {
        int r = p * 16 + rr;  // n offset
        u32x2 o = { pkbf(T[cc][r], T[cc + 1][r]), pkbf(T[cc + 2][r], T[cc + 3][r]) };
        *(u32x2*)&WT[(size_t)(n0 + r) * EMBED + k0 + cc] = o;
    }
}

// ============================================================================
// R17 GEMM: m97-exact 128x128 structure, occupancy-first.
// Rationale: three 8-phase variants all idle ~69% (R10 PMC: MfmaUtil 21.6 +
// VALUBusy 9.9) because at 1 blk/CU a non-forming intra-block pipeline has no
// other block to cover its drains.  m97's verified 874 TF comes from the
// SIMPLE 2-barrier loop + ~3-4 blocks/CU of cross-block TLP (m114).  So:
// 128^2 tile, 256 thr (2x2 waves, 64x64/wave), BK=64, 32 KB LDS single-buf,
// launch_bounds(256,4) -> 4 blocks/CU (128 KB LDS, VGPR<=128).  Per K-step
// per wave: 32 MFMA : 16 ds_read_b128 (2:1, best ratio of all variants).
// Staggered block completion backfills the grid (no cross-block lockstep).
// mode 0: combined QKV (BT = [3072][1024]); 128-col blocks never straddle
// Q/K/V (1024%128==0): z = colblk>>10 -> Q bf16 (bias pre-scaled SL2E) /
// K bf16 / Vt[bh][d][s].   mode 1: fp32 row-major out.
// ============================================================================
__global__ __launch_bounds__(256, 4) void gemm_sq128(const short* __restrict__ A,
                                                     const short* __restrict__ BT,
                                                     const float* __restrict__ b0,
                                                     const float* __restrict__ b1,
                                                     const float* __restrict__ b2,
                                                     void* __restrict__ C0,
                                                     void* __restrict__ C1,
                                                     void* __restrict__ C2,
                                                     int mode) {
    __shared__ short As[128 * 64];   // [row][k], 16 KB, 16B chunks XOR-swizzled
    __shared__ short Bs[128 * 64];   // [col(n)][k], 16 KB
    const int tid = threadIdx.x;
    const int lane = tid & 63;
    const int wid = tid >> 6;
    const int c16 = lane & 15, quad = lane >> 4, sw = c16 & 7;
    const int wm = wid >> 1, wn = wid & 1;            // 2x2 wave grid, 64x64 each
    // T1: bijective chunked XCD swizzle (1536 and 512 blocks, both % 8 == 0)
    const int gx = gridDim.x;
    const int hid = blockIdx.y * gx + blockIdx.x;
    const int cpx = (gx * gridDim.y) >> 3;
    const int tle = (hid & 7) * cpx + (hid >> 3);
    const int bx = tle % gx, by = tle / gx;
    const int rowblk = by * 128, colblk = bx * 128;

    // staging: thread owns 16B chunks ci = p*256 + tid, p=0..3, per matrix.
    // row = ci>>3 = p*32 + (tid>>3); k-chunk g = (ci&7)^(row&7) — p-invariant
    // since p*32 = 0 (mod 8).  Read-side XOR swizzle inverse pre-applied to
    // the GLOBAL source; LDS dest linear (dest = ci*16B).
    const int r0 = tid >> 3;                          // 0..31
    const int g0 = (tid & 7) ^ (r0 & 7);
    const short* aS = A + (size_t)(rowblk + r0) * EMBED + g0 * 8;
    const short* bS = BT + (size_t)(colblk + r0) * EMBED + g0 * 8;

    f32x4 acc[4][4] = {};            // [fm][fn]

    #pragma unroll 1
    for (int k0 = 0; k0 < EMBED; k0 += 64) {
        #pragma unroll
        for (int p = 0; p < 4; ++p)
            async16(aS + p * (32 * EMBED) + k0, &As[tid * 8 + p * 2048]);
        #pragma unroll
        for (int p = 0; p < 4; ++p)
            async16(bS + p * (32 * EMBED) + k0, &Bs[tid * 8 + p * 2048]);
        __syncthreads();
        #pragma unroll
        for (int ks = 0; ks < 2; ++ks) {
            bf16x8 af[4], bfr[4];
            #pragma unroll
            for (int fm = 0; fm < 4; ++fm)
                af[fm] = *(const bf16x8*)&As[(wm * 64 + fm * 16 + c16) * 64 + ((ks * 4 + quad) ^ sw) * 8];
            #pragma unroll
            for (int fn = 0; fn < 4; ++fn)
                bfr[fn] = *(const bf16x8*)&Bs[(wn * 64 + fn * 16 + c16) * 64 + ((ks * 4 + quad) ^ sw) * 8];
            #pragma unroll
            for (int fm = 0; fm < 4; ++fm)
                #pragma unroll
                for (int fn = 0; fn < 4; ++fn)
                    acc[fm][fn] = __builtin_amdgcn_mfma_f32_16x16x32_bf16(af[fm], bfr[fn], acc[fm][fn], 0, 0, 0);
        }
        __syncthreads();
    }

    // epilogue: C/D frag layout col = lane&15, row = quad*4 + reg
    const int rb0 = rowblk + wm * 64 + quad * 4;
    const int cb0 = wn * 64 + c16;
    if (mode == 0) {
        const int z = colblk >> 10;               // Q / K / V selector
        const int cm = colblk & 1023;
        const float* bias = (z == 0) ? b0 : (z == 1) ? b1 : b2;
        if (z == 2) {
            short* Vt = (short*)C2;               // Vt[bh][d][s], 4 consecutive s per frag
            #pragma unroll
            for (int fm = 0; fm < 4; ++fm) {
                const int row = rb0 + fm * 16;
                const int b = row >> 11, s = row & 2047;
                #pragma unroll
                for (int fn = 0; fn < 4; ++fn) {
                    const int cv = cm + cb0 + fn * 16;
                    const int head = cv >> 6, d = cv & 63;
                    const float bv = bias[cv];
                    u32x2 o = { pkbf(acc[fm][fn][0] + bv, acc[fm][fn][1] + bv),
                                pkbf(acc[fm][fn][2] + bv, acc[fm][fn][3] + bv) };
                    *(u32x2*)&Vt[((size_t)(b * NHEADS + head) * HDIM + d) * SEQ + s] = o;
                }
            }
        } else {
            short* Cq = (short*)((z == 0) ? C0 : C1);
            const float bsc = (z == 0) ? SL2E : 1.0f;
            #pragma unroll
            for (int fm = 0; fm < 4; ++fm) {
                const int row = rb0 + fm * 16;
                #pragma unroll
                for (int fn = 0; fn < 4; ++fn) {
                    const int col = cm + cb0 + fn * 16;
                    const float bv = bias[col] * bsc;
                    #pragma unroll
                    for (int r = 0; r < 4; ++r)
                        Cq[(size_t)(row + r) * EMBED + col] = f2bf(acc[fm][fn][r] + bv);
                }
            }
        }
    } else {
        float* Co = (float*)C0;
        #pragma unroll
        for (int fm = 0; fm < 4; ++fm) {
            const int row = rb0 + fm * 16;
            #pragma unroll
            for (int fn = 0; fn < 4; ++fn) {
                const int col = colblk + cb0 + fn * 16;
                const float bv = b0[col];
                #pragma unroll
                for (int r = 0; r < 4; ++r)
                    Co[(size_t)(row + r) * EMBED + col] = acc[fm][fn][r] + bv;
            }
        }
    }
}

// ---------- MFMA flash attention v5.1 (R17): R16 + cvt_pk P-pack ----------
// R16 counters: MfmaUtil 37.4 + VALUBusy 55.5 = 93% combined issue at 4
// blocks/CU -> near the dual-pipe limit; remaining lever is VALU-op count.
// v_cvt_pk_bf16_f32 (1 inst) replaces pkbf's add+add+perm (3 insts) in the
// P-pack path: -32 VALU ops per tile (~13% of tile VALU).  RTNE (vs RTNA).
__global__ __launch_bounds__(256, 4) void attn_mfma(const short* __restrict__ Qb,
                                                    const short* __restrict__ Kb,
                                                    const short* __restrict__ Vt,
                                                    short* __restrict__ Ob) {
    __shared__ short SH[16384];      // kb[2] @ 0/4096, vb[2] @ 8192/12288 (shorts)
    const int tid = threadIdx.x;
    const int wave = tid >> 6, lane = tid & 63;
    const int l31 = lane & 31, h = lane >> 5;
    const int swz = l31 & 7;
    // T1 swizzle: grid (16 qb, 64 bh) = 1024 blocks
    const int hid = blockIdx.y * 16 + blockIdx.x;
    const int tle = (hid & 7) * 128 + (hid >> 3);
    const int qb = tle & 15, bh = tle >> 4;
    const int b = bh >> 4, hd = bh & 15;
    const size_t base = (size_t)b * SEQ * EMBED + (size_t)hd * HDIM;
    const size_t vbase = (size_t)bh * HDIM * SEQ;
    const int q0 = qb * 128;

    // Q B-frags for the whole kernel: n=q=l31, k(d) = ks*16 + h*8 + j
    bf16x8 qf[4];
    #pragma unroll
    for (int ks = 0; ks < 4; ++ks)
        qf[ks] = *(const bf16x8*)&Qb[base + (size_t)(q0 + wave * 32 + l31) * EMBED + ks * 16 + h * 8];

    // hoisted staging pointers (advance by constant per staged tile)
    const short* kp[2];
    const short* vp[2];
    int ldofs[2];
    #pragma unroll
    for (int it = 0; it < 2; ++it) {
        int ci = (it * 4 + wave) * 64 + lane;
        int row = ci >> 3, g = (ci & 7) ^ (row & 7);
        kp[it] = Kb + base + (size_t)row * EMBED + g * 8;
        vp[it] = Vt + vbase + (size_t)row * SEQ + g * 8;
        ldofs[it] = (it * 4 + wave) * 512;          // wave-uniform LDS base
    }

#define STAGE_KV(J) do { \
    async16(kp[0], &SH[(J) * 4096 + ldofs[0]]); \
    async16(kp[1], &SH[(J) * 4096 + ldofs[1]]); \
    async16(vp[0], &SH[8192 + (J) * 4096 + ldofs[0]]); \
    async16(vp[1], &SH[8192 + (J) * 4096 + ldofs[1]]); \
    kp[0] += 64 * EMBED; kp[1] += 64 * EMBED; \
    vp[0] += 64; vp[1] += 64; \
} while (0)

    f32x16 O[2] = {};
    f32x2 ls = {0.0f, 0.0f};

    // prologue: stage tile 0 into buf0
    STAGE_KV(0);
    asm volatile("s_waitcnt vmcnt(0)" ::: "memory");
    __builtin_amdgcn_s_barrier();

// One K/V tile from buffer CUR; optionally stage tile t+1 into buf NXT first.
// Per-nt half: QK(nt) 4 MFMA -> exp/pack (8 exp-pairs, 8 pk words via cvt_pk)
// -> PV steps ks=2nt,2nt+1 (4 MFMA).  S-liveness = one f32x16, pk = 8 regs.
#define ATT_TILE(CUR, NXT, DO_STAGE) do { \
    if (DO_STAGE) STAGE_KV(NXT); \
    _Pragma("unroll") \
    for (int nt = 0; nt < 2; ++nt) { \
        f32x16 st = {0.0f, 0.0f, 0.0f, 0.0f, 0.0f, 0.0f, 0.0f, 0.0f, \
                     0.0f, 0.0f, 0.0f, 0.0f, 0.0f, 0.0f, 0.0f, 0.0f}; \
        __builtin_amdgcn_s_setprio(1); \
        _Pragma("unroll") \
        for (int ks = 0; ks < 4; ++ks) { \
            bf16x8 ak = *(const bf16x8*)&SH[(CUR) * 4096 + (nt * 32 + l31) * 64 + ((ks * 2 + h) ^ swz) * 8]; \
            st = __builtin_amdgcn_mfma_f32_32x32x16_bf16(ak, qf[ks], st, 0, 0, 0); \
        } \
        __builtin_amdgcn_s_setprio(0); \
        u32 pk[8]; \
        _Pragma("unroll") \
        for (int i = 0; i < 8; ++i) { \
            float e0 = fexp2(st[2 * i]), e1 = fexp2(st[2 * i + 1]); \
            f32x2 e = { e0, e1 }; \
            ls += e; \
            pk[i] = cvtpk(e0, e1); \
        } \
        __builtin_amdgcn_s_setprio(1); \
        _Pragma("unroll") \
        for (int kk = 0; kk < 2; ++kk) { \
            const int ks = nt * 2 + kk, bs = kk * 4; \
            u32x4 fr; \
            i32x2 sA = __builtin_amdgcn_permlane32_swap((int)pk[bs + 0], (int)pk[bs + 2], false, false); \
            i32x2 sB = __builtin_amdgcn_permlane32_swap((int)pk[bs + 1], (int)pk[bs + 3], false, false); \
            fr.x = (u32)sA.x; fr.y = (u32)sB.x; fr.z = (u32)sA.y; fr.w = (u32)sB.y; \
            bf16x8 pf = __builtin_bit_cast(bf16x8, fr); \
            _Pragma("unroll") \
            for (int mt = 0; mt < 2; ++mt) { \
                bf16x8 vf = *(const bf16x8*)&SH[8192 + (CUR) * 4096 + (mt * 32 + l31) * 64 + ((ks * 2 + h) ^ swz) * 8]; \
                O[mt] = __builtin_amdgcn_mfma_f32_32x32x16_bf16(vf, pf, O[mt], 0, 0, 0); \
            } \
        } \
        __builtin_amdgcn_s_setprio(0); \
    } \
    asm volatile("s_waitcnt vmcnt(0)" ::: "memory"); \
    __builtin_amdgcn_s_barrier(); \
} while (0)

    // tiles 0..30 stage t+1; tile 31 computes only
    #pragma unroll 1
    for (int t = 0; t < 30; t += 2) {
        ATT_TILE(0, 1, 1);
        ATT_TILE(1, 0, 1);
    }
    ATT_TILE(0, 1, 1);   // t=30, stages 31 -> buf1
    ATT_TILE(1, 0, 0);   // t=31

#undef ATT_TILE
#undef STAGE_KV

    // finalize: partner lane holds the other half of this q's key-sum
    float lsum = ls.x + ls.y;
    lsum += __shfl_xor(lsum, 32);
    float inv = 1.0f / lsum;

    // O^T[d][q]: col=q=l31, d = mt*32 + (reg&3) + 8*(reg>>2) + 4h.
    // Write bf16 to LDS (XOR-swizzled 8B units), then read rows -> coalesced.
    const int wbase = wave * 2048;
    #pragma unroll
    for (int mt = 0; mt < 2; ++mt)
        #pragma unroll
        for (int m = 0; m < 4; ++m) {
            u32x2 wv;
            wv.x = pkbf(O[mt][4 * m + 0] * inv, O[mt][4 * m + 1] * inv);
            wv.y = pkbf(O[mt][4 * m + 2] * inv, O[mt][4 * m + 3] * inv);
            int u = mt * 8 + 2 * m + h;               // 8B unit index (d = u*4)
            int su = u ^ ((l31 & 7) << 1);
            *(u32x2*)&SH[wbase + l31 * 64 + su * 4] = wv;
        }
    __syncthreads();
    // full tile = 1024 x 16B chunks (4 waves x 32 q x 8 d-chunks)
    #pragma unroll
    for (int p = 0; p < 4; ++p) {
        int ci = p * 256 + tid;
        int wq = ci >> 8, rem = ci & 255;
        int r = rem >> 3, cch = rem & 7;
        int su = (2 * cch) ^ ((r & 7) << 1);
        bf16x8 val = *(const bf16x8*)&SH[wq * 2048 + r * 64 + su * 4];
        *(bf16x8*)&Ob[base + (size_t)(q0 + wq * 32 + r) * EMBED + cch * 8] = val;
    }
}

extern "C" void kernel_launch(void* const* d_in, const int* in_sizes, int n_in,
                              void* d_out, int out_size, void* d_ws, size_t ws_size,
                              hipStream_t stream)
{
    const float* X  = (const float*)d_in[0];
    const float* Wq = (const float*)d_in[1];
    const float* bq = (const float*)d_in[2];
    const float* Wk = (const float*)d_in[3];
    const float* bk = (const float*)d_in[4];
    const float* Wv = (const float*)d_in[5];
    const float* bv = (const float*)d_in[6];
    const float* Wo = (const float*)d_in[7];
    const float* bo = (const float*)d_in[8];
    float* out = (float*)d_out;

    const size_t NE = (size_t)ROWS * EMBED;       // 8M elements
    short* Xbf = (short*)d_ws;                    // 16 MB
    short* Qb  = Xbf + NE;                        // 16 MB (also attention O)
    short* Kb  = Qb + NE;                         // 16 MB
    short* Vtb = Kb + NE;                         // 16 MB  [bh][d][s]
    short* WqT = Vtb + NE;                        // 2 MB each; WqT/WkT/WvT are
    short* WkT = WqT + (size_t)EMBED * EMBED;     //   CONTIGUOUS = combined
    short* WvT = WkT + (size_t)EMBED * EMBED;     //   Wqkv^T [3072][1024]
    short* WoT = WvT + (size_t)EMBED * EMBED;     // total 72 MB

    convert_f32_bf16<<<(ROWS * EMBED) / 1024, 256, 0, stream>>>(X, Xbf);
    dim3 gw(16, 16, 4);
    transpose_w4<<<gw, 256, 0, stream>>>(Wq, Wk, Wv, Wo, WqT, WkT, WvT, WoT);

    // combined QKV: grid (3072/128, 8192/128) = (24,64) = 1536 blocks, 4/CU
    dim3 gq(24, 64, 1);
    gemm_sq128<<<gq, 256, 0, stream>>>(Xbf, WqT, bq, bk, bv, Qb, Kb, Vtb, 0);

    dim3 gt(SEQ / 128, BATCH * NHEADS);           // (16, 64)
    attn_mfma<<<gt, 256, 0, stream>>>(Qb, Kb, Vtb, Qb);   // O aliases Qb

    // out-proj: grid (1024/128, 8192/128) = (8,64) = 512 blocks, 4/CU
    dim3 gg(8, 64, 1);
    gemm_sq128<<<gg, 256, 0, stream>>>(Qb, WoT, bo, bo, bo, out, out, out, 1);
}